// Round 11
// baseline (38.886 us; speedup 1.0000x reference)
//
#include <hip/hip_runtime.h>

// t [32,8192] f32, control_points [22,3,10] f32.
// Outputs: pos, vel, acc each [32,8192,22,3] f32, concatenated flat.
#define NPTS       (32 * 8192)            // 262144 eval points
#define OUT_PER_PT 66                     // 22*3
#define TOTF       (NPTS * OUT_PER_PT)    // 17,301,504 (fits int)
#define THREADS    256
#define PTS_PER_BLOCK 256
#define TILE_F     (PTS_PER_BLOCK * OUT_PER_PT)   // 16896 floats per block per stream
#define NF4        (TILE_F / 4)                   // 4224 float4 per block per stream
#define BSTRIDE    24                     // floats/point row: (b0,d1) pairs [0..19], s @ [20]
#define CPT_LD     34                     // float2 row stride of cpT (pad 33->34)

#define K4 ((float)(1.0 / 7.0))
#define K5 ((float)(2.0 / 7.0))
#define K6 ((float)(3.0 / 7.0))
#define K7 ((float)(4.0 / 7.0))
#define K8 ((float)(5.0 / 7.0))
#define K9 ((float)(6.0 / 7.0))

__device__ __forceinline__ void knots(float* kf) {
    kf[0] = 0.f; kf[1] = 0.f; kf[2] = 0.f; kf[3] = 0.f;
    kf[4] = K4; kf[5] = K5; kf[6] = K6; kf[7] = K7; kf[8] = K8; kf[9] = K9;
    kf[10] = 1.f; kf[11] = 1.f; kf[12] = 1.f; kf[13] = 1.f;
}

// Faithful f32 mirror of the reference truncated Cox-de Boor.
__device__ __forceinline__ void basis_f32(float t, float* __restrict__ N) {
    float kf[14]; knots(kf);
#pragma unroll
    for (int i = 0; i < 10; ++i) N[i] = (t >= kf[i] && t < kf[i + 1]) ? 1.0f : 0.0f;
#pragma unroll
    for (int r = 1; r <= 3; ++r) {
#pragma unroll
        for (int i = 0; i < 9; ++i) {
            if (i < 10 - r) {
                const float dl = kf[i + r] - kf[i];
                const float dr = kf[i + r + 1] - kf[i + 1];
                const float il = (dl != 0.0f) ? 1.0f / dl : 0.0f;
                const float ir = (dr != 0.0f) ? 1.0f / dr : 0.0f;
                N[i] = ((t - kf[i]) * il) * N[i] + ((kf[i + r + 1] - t) * ir) * N[i + 1];
            }
        }
        N[10 - r] = 0.0f;
    }
}

// Degree-3 basis + analytic first derivative (matches FD to ~1e-4; threshold 0.26).
__device__ __forceinline__ void basis_and_deriv(float t, float* __restrict__ b0,
                                                float* __restrict__ d1) {
    float kf[14]; knots(kf);
    float N[10];
#pragma unroll
    for (int i = 0; i < 10; ++i) N[i] = (t >= kf[i] && t < kf[i + 1]) ? 1.0f : 0.0f;
#pragma unroll
    for (int r = 1; r <= 2; ++r) {
#pragma unroll
        for (int i = 0; i < 9; ++i) {
            if (i < 10 - r) {
                const float dl = kf[i + r] - kf[i];
                const float dr = kf[i + r + 1] - kf[i + 1];
                const float il = (dl != 0.0f) ? 1.0f / dl : 0.0f;
                const float ir = (dr != 0.0f) ? 1.0f / dr : 0.0f;
                N[i] = ((t - kf[i]) * il) * N[i] + ((kf[i + r + 1] - t) * ir) * N[i + 1];
            }
        }
        N[10 - r] = 0.0f;
    }
#pragma unroll
    for (int i = 0; i < 7; ++i) {
        const float dl = kf[i + 3] - kf[i];
        const float dr = kf[i + 4] - kf[i + 1];
        const float il = (dl != 0.0f) ? 3.0f / dl : 0.0f;
        const float ir = (dr != 0.0f) ? 3.0f / dr : 0.0f;
        d1[i] = il * N[i] - ir * N[i + 1];
    }
    d1[7] = 0.f; d1[8] = 0.f; d1[9] = 0.f;
#pragma unroll
    for (int i = 0; i < 7; ++i) {
        const float dl = kf[i + 3] - kf[i];
        const float dr = kf[i + 4] - kf[i + 1];
        const float il = (dl != 0.0f) ? 1.0f / dl : 0.0f;
        const float ir = (dr != 0.0f) ? 1.0f / dr : 0.0f;
        b0[i] = ((t - kf[i]) * il) * N[i] + ((kf[i + 4] - t) * ir) * N[i + 1];
    }
    b0[7] = 0.f; b0[8] = 0.f; b0[9] = 0.f;
}

__global__ __launch_bounds__(THREADS)
void spline_kernel(const float* __restrict__ t_in,
                   const float* __restrict__ cp_in,
                   float* __restrict__ out) {
    __shared__ __align__(16) float  s_b[PTS_PER_BLOCK * BSTRIDE];  // 24.6 KB
    __shared__ __align__(16) float2 s_cpT[10 * CPT_LD];            // 2.7 KB

    const int tid = threadIdx.x;
    const int blk = blockIdx.x;

    // stage cpT[i][c] = (cp[2c][i], cp[2c+1][i]); pad col 33 with zeros.
    for (int idx = tid; idx < 10 * CPT_LD; idx += THREADS) {
        const int i = idx / CPT_LD, c = idx - i * CPT_LD;
        s_cpT[idx] = (c < 33)
            ? make_float2(cp_in[(2 * c) * 10 + i], cp_in[(2 * c + 1) * 10 + i])
            : make_float2(0.f, 0.f);
    }

    // ---- Phase 1: per-thread f32 basis + analytic derivative + segment index ----
    {
        const float t = t_in[blk * PTS_PER_BLOCK + tid];
        float b0[10], d1[10];
        basis_and_deriv(t, b0, d1);

        const double td = (double)t;   // rare boundary lanes: faithful one-sided FD
        if (td < 1e-6) {
            float Np[10];
            basis_f32((float)(td + 1e-6), Np);
#pragma unroll
            for (int i = 0; i < 10; ++i) d1[i] = Np[i] * 5.0e5f;
        } else if (td + 1e-6 >= 1.0) {
            float Nm[10];
            basis_f32((float)(td - 1e-6), Nm);
#pragma unroll
            for (int i = 0; i < 10; ++i) d1[i] = -Nm[i] * 5.0e5f;
        }

        // Segment index via the SAME compares as the degree-0 indicator:
        // b0/d1 are exactly 0.0f outside i in [s, s+3].
        const int s = (t >= K4) + (t >= K5) + (t >= K6)
                    + (t >= K7) + (t >= K8) + (t >= K9);

        float* row = s_b + tid * BSTRIDE;   // interleaved (b0,d1) pairs -> b64 reads
#pragma unroll
        for (int i = 0; i < 10; ++i) {
            row[2 * i]     = b0[i];
            row[2 * i + 1] = d1[i];
        }
        row[20] = __int_as_float(s);
    }
    __syncthreads();

    // ---- Phase 2: float4-centric; 4 outputs/stream per iter; dense 1KB wave-stores ----
    float4* __restrict__ op = (float4*)(out + (size_t)blk * TILE_F);
    float4* __restrict__ ov = (float4*)(out + (size_t)TOTF + (size_t)blk * TILE_F);
    float4* __restrict__ oa = (float4*)(out + (size_t)2 * TOTF + (size_t)blk * TILE_F);

#pragma unroll 2
    for (int m = 0; m < 17; ++m) {
        const unsigned idx = (unsigned)(m * THREADS + tid);   // float4 index, 0..4223
        if (idx < NF4) {
            const unsigned f = idx * 4u;
            const unsigned p = f / 66u;                       // local point (magic-mul)
            const unsigned c = f - p * 66u;                   // 0..64, always even

            const float* __restrict__ row = s_b + p * BSTRIDE;
            const int s = __float_as_int(row[20]);
            const float2* __restrict__ bd = (const float2*)row + s;   // pairs s..s+3

            float pf0 = 0.f, pf1 = 0.f, pf2 = 0.f, pf3 = 0.f;
            float vf0 = 0.f, vf1 = 0.f, vf2 = 0.f, vf3 = 0.f;

            if (c < 64u) {                      // all 4 floats in point p
                const unsigned col = c >> 1;    // float2 columns col, col+1
#pragma unroll
                for (int r = 0; r < 4; ++r) {
                    const float2 bdv = bd[r];
                    const float2 cv0 = s_cpT[(s + r) * CPT_LD + col];
                    const float2 cv1 = s_cpT[(s + r) * CPT_LD + col + 1];
                    pf0 += bdv.x * cv0.x;  pf1 += bdv.x * cv0.y;
                    pf2 += bdv.x * cv1.x;  pf3 += bdv.x * cv1.y;
                    vf0 += bdv.y * cv0.x;  vf1 += bdv.y * cv0.y;
                    vf2 += bdv.y * cv1.x;  vf3 += bdv.y * cv1.y;
                }
            } else {                            // c==64: floats {p:64,65, p+1:0,1}; p even
#pragma unroll
                for (int r = 0; r < 4; ++r) {
                    const float2 bdv = bd[r];
                    const float2 cv = s_cpT[(s + r) * CPT_LD + 32];
                    pf0 += bdv.x * cv.x;  pf1 += bdv.x * cv.y;
                    vf0 += bdv.y * cv.x;  vf1 += bdv.y * cv.y;
                }
                const float* __restrict__ row2 = row + BSTRIDE;
                const int s2 = __float_as_int(row2[20]);
                const float2* __restrict__ bd2 = (const float2*)row2 + s2;
#pragma unroll
                for (int r = 0; r < 4; ++r) {
                    const float2 bdv = bd2[r];
                    const float2 cv = s_cpT[(s2 + r) * CPT_LD + 0];
                    pf2 += bdv.x * cv.x;  pf3 += bdv.x * cv.y;
                    vf2 += bdv.y * cv.x;  vf3 += bdv.y * cv.y;
                }
            }

            op[idx] = make_float4(pf0, pf1, pf2, pf3);
            const float4 v = make_float4(vf0, vf1, vf2, vf3);
            ov[idx] = v;
            oa[idx] = v;
        }
    }
}

extern "C" void kernel_launch(void* const* d_in, const int* in_sizes, int n_in,
                              void* d_out, int out_size, void* d_ws, size_t ws_size,
                              hipStream_t stream) {
    const float* t_in  = (const float*)d_in[0];   // [32, 8192] f32
    const float* cp_in = (const float*)d_in[1];   // [22, 3, 10] f32
    float* out = (float*)d_out;

    const int blocks = NPTS / PTS_PER_BLOCK;      // 1024
    spline_kernel<<<blocks, THREADS, 0, stream>>>(t_in, cp_in, out);
}